// Round 11
// baseline (73.516 us; speedup 1.0000x reference)
//
#include <hip/hip_runtime.h>
#include <math.h>
#include <utility>

namespace {

constexpr int C_  = 16;
constexpr int OR_ = 8;
constexpr int H_  = 192;
constexpr int W_  = 192;
constexpr int HW_ = H_ * W_;
constexpr int CH_ = OR_ * HW_;
constexpr float PI_F = 3.14159265358979323846f;

// Padded conv-output workspace: image px (y,x) -> padded (y+2, x+2).
constexpr int PH_  = 196;             // 192 + 2 + 2
constexpr int PW_  = 208;             // 2 + 192 + 14 (row = 832 B, 16B multiple)
constexpr int PPL_ = PH_ * PW_;       // 40768 floats per plane
constexpr int NPL_ = C_ * OR_;        // 128 planes
constexpr int PAD_CELLS = 2 * PW_ + 2 * PW_ + H_ * 16;   // 3904 border cells/plane
constexpr int PAD_PER_BLOCK = 217;                        // 18 blocks/plane * 217 >= 3904

// dword-aligned float4 (CDNA global multi-dword loads need only 4B alignment)
typedef float f4u __attribute__((ext_vector_type(4), aligned(4)));

constexpr float SQ2H = 0.70710678118654752440f;
constexpr float CT8[8] = { 1.0f,  SQ2H,  0.0f, -SQ2H, -1.0f, -SQ2H,  0.0f,  SQ2H };
constexpr float ST8[8] = { 0.0f,  SQ2H,  1.0f,  SQ2H,  0.0f, -SQ2H, -1.0f, -SQ2H };

constexpr int cfloor(float v) {
    return (v >= 0.0f) ? (int)v : (((float)(int)v == v) ? (int)v : (int)v - 1);
}

// Zero-padded corner fetch (matches reference _sample's per-corner validity).
__device__ __forceinline__ float corner(const float* __restrict__ p, int iy, int ix) {
    bool valid = ((unsigned)iy < (unsigned)H_) && ((unsigned)ix < (unsigned)W_);
    int yc = min(max(iy, 0), H_ - 1);
    int xc = min(max(ix, 0), W_ - 1);
    float v = p[yc * W_ + xc];
    return valid ? v : 0.0f;
}

// ---------------- convection_m2: 8 px per thread (x-vectorized) --------------
// Writes PADDED layout; also zeroes this block's slice of the pad border.
__global__ __launch_bounds__(256) void conv_kernel(
        const float* __restrict__ u, const float* __restrict__ g0,
        float* __restrict__ wsA) {
    const int t = threadIdx.x;
    const int xg  = t & 7;            // 8 groups of 8 px = 64 wide
    const int row = t >> 3;           // 0..31
    const int x0t = blockIdx.x * 64 + xg * 8;
    const int y   = blockIdx.y * 32 + row;
    const int z = blockIdx.z;
    const int c  = z >> 3;
    const int th = z & 7;

    // ---- pad-border zeroing (idempotent; 18 blocks/plane x 217 cells) ----
    {
        const int bi = blockIdx.y * 3 + blockIdx.x;          // 0..17
        const int idx = bi * PAD_PER_BLOCK + t;
        if (t < PAD_PER_BLOCK && idx < PAD_CELLS) {
            int i = idx, r, col;
            if (i < 2 * PW_)        { r = i / PW_;           col = i - (i / PW_) * PW_; }
            else if (i < 4 * PW_)   { i -= 2 * PW_; r = 194 + i / PW_; col = i - (i / PW_) * PW_; }
            else { i -= 4 * PW_; r = 2 + (i >> 4); const int cs = i & 15;
                   col = (cs < 2) ? cs : (192 + cs); }
            wsA[z * PPL_ + r * PW_ + col] = 0.0f;
        }
    }

    // ---- per-(c,th) conv params ----
    const float gx0  = g0[c * 3 + 0];
    const float gy0  = g0[c * 3 + 1];
    const float gth0 = g0[c * 3 + 2];

    float sa, ca;
    sincosf((float)th * (2.0f * PI_F / OR_) - gth0, &sa, &ca);
    const float dxs = ca * gx0 - sa * gy0;
    const float dys = sa * gx0 + ca * gy0;
    const float mx = -dxs, my = -dys;
    const float fxi = floorf(mx), fyi = floorf(my);
    const float wx = mx - fxi, wy = my - fyi;
    const int sxo = (int)fxi, syo = (int)fyi;

    float tc = (float)th - gth0 * (OR_ / (2.0f * PI_F));
    tc = tc - floorf(tc * (1.0f / OR_)) * (float)OR_;
    const float t0f = floorf(tc);
    const float wt = tc - t0f;
    const int t0i = ((int)t0f) & 7;
    const int t1i = (t0i + 1) & 7;
    const float* __restrict__ p0 = u + c * CH_ + t0i * HW_;
    const float* __restrict__ p1 = u + c * CH_ + t1i * HW_;

    const int colL = x0t + sxo;       // left corner col of px j=0
    const int rowT = y + syo;         // top corner row

    float r8[8];
    if (colL >= 0 && colL + 8 < W_ && rowT >= 0 && rowT + 1 < H_) {
        const int o = rowT * W_ + colL;
        const f4u a0 = *(const f4u*)(p0 + o);
        const f4u a1 = *(const f4u*)(p0 + o + 4);
        const float a2 = p0[o + 8];
        const f4u b0 = *(const f4u*)(p0 + o + W_);
        const f4u b1 = *(const f4u*)(p0 + o + W_ + 4);
        const float b2 = p0[o + W_ + 8];
        const f4u c0 = *(const f4u*)(p1 + o);
        const f4u c1 = *(const f4u*)(p1 + o + 4);
        const float c2 = p1[o + 8];
        const f4u d0 = *(const f4u*)(p1 + o + W_);
        const f4u d1 = *(const f4u*)(p1 + o + W_ + 4);
        const float d2 = p1[o + W_ + 8];
        const float R00[9] = {a0[0],a0[1],a0[2],a0[3],a1[0],a1[1],a1[2],a1[3],a2};
        const float R01[9] = {b0[0],b0[1],b0[2],b0[3],b1[0],b1[1],b1[2],b1[3],b2};
        const float R10[9] = {c0[0],c0[1],c0[2],c0[3],c1[0],c1[1],c1[2],c1[3],c2};
        const float R11[9] = {d0[0],d0[1],d0[2],d0[3],d1[0],d1[1],d1[2],d1[3],d2};
        #pragma unroll
        for (int j = 0; j < 8; ++j) {
            const float h00 = R00[j] + wx * (R00[j + 1] - R00[j]);
            const float h01 = R01[j] + wx * (R01[j + 1] - R01[j]);
            const float h10 = R10[j] + wx * (R10[j + 1] - R10[j]);
            const float h11 = R11[j] + wx * (R11[j + 1] - R11[j]);
            const float v0 = h00 + wy * (h01 - h00);
            const float v1 = h10 + wy * (h11 - h10);
            r8[j] = v0 + wt * (v1 - v0);
        }
    } else {
        const float w00 = (1.f - wy) * (1.f - wx);
        const float w01 = (1.f - wy) * wx;
        const float w10 = wy * (1.f - wx);
        const float w11 = wy * wx;
        #pragma unroll
        for (int j = 0; j < 8; ++j) {
            const int ix = colL + j;
            const float v0 = w00 * corner(p0, rowT, ix)     + w01 * corner(p0, rowT, ix + 1)
                           + w10 * corner(p0, rowT + 1, ix) + w11 * corner(p0, rowT + 1, ix + 1);
            const float v1 = w00 * corner(p1, rowT, ix)     + w01 * corner(p1, rowT, ix + 1)
                           + w10 * corner(p1, rowT + 1, ix) + w11 * corner(p1, rowT + 1, ix + 1);
            r8[j] = v0 + wt * (v1 - v0);
        }
    }

    float* __restrict__ op = wsA + z * PPL_ + (y + 2) * PW_ + (x0t + 2);
    f4u s0 = { r8[0], r8[1], r8[2], r8[3] };
    f4u s1 = { r8[4], r8[5], r8[6], r8[7] };
    *(f4u*)op = s0;
    *(f4u*)(op + 4) = s1;
}

// ---------------- dilation: 4x2 px per thread, 6x8 register windows ----------
template<int TH, int PP, int OO>
__device__ __forceinline__ void off_one(const float (&w)[6][8],
        const float* __restrict__ sk, float (&ac0)[4], float (&ac1)[4]) {
    constexpr int hxi = OO % 3 - 1;
    constexpr int hyi = OO / 3 - 1;
    constexpr float ct = CT8[TH];
    constexpr float st = ST8[TH];
    constexpr float sx = ct * (float)hxi - st * (float)hyi;
    constexpr float sy = st * (float)hxi + ct * (float)hyi;
    constexpr int dx = cfloor(sx);
    constexpr int dy = cfloor(sy);
    constexpr float wx = sx - (float)dx;
    constexpr float wy = sy - (float)dy;
    constexpr int R  = dy + 2;    // 0..3
    constexpr int Cb = dx + 2;    // 0..3

    const float k = sk[PP * 9 + OO];   // wave-uniform LDS broadcast
    #pragma unroll
    for (int j = 0; j < 4; ++j) {
        float v0, v1;
        if constexpr (wx == 0.0f && wy == 0.0f) {
            v0 = w[R][Cb + j];
            v1 = w[R + 1][Cb + j];
        } else if constexpr (wy == 0.0f) {
            const float a = w[R][Cb + j],     a1 = w[R][Cb + j + 1];
            const float b = w[R + 1][Cb + j], b1 = w[R + 1][Cb + j + 1];
            v0 = a + wx * (a1 - a);
            v1 = b + wx * (b1 - b);
        } else if constexpr (wx == 0.0f) {
            const float a = w[R][Cb + j];
            const float b = w[R + 1][Cb + j];
            const float cc = w[R + 2][Cb + j];
            v0 = a + wy * (b - a);
            v1 = b + wy * (cc - b);
        } else {
            const float a = w[R][Cb + j],     a1 = w[R][Cb + j + 1];
            const float b = w[R + 1][Cb + j], b1 = w[R + 1][Cb + j + 1];
            const float cc = w[R + 2][Cb + j], cc1 = w[R + 2][Cb + j + 1];
            const float h0 = a + wx * (a1 - a);
            const float h1 = b + wx * (b1 - b);
            const float h2 = cc + wx * (cc1 - cc);
            v0 = h0 + wy * (h1 - h0);
            v1 = h1 + wy * (h2 - h1);
        }
        ac0[j] = fmaxf(ac0[j], v0 - k);
        ac1[j] = fmaxf(ac1[j], v1 - k);
    }
}

template<int TH, int PP, int... OOs>
__device__ __forceinline__ void off_nine(std::integer_sequence<int, OOs...>,
        const float (&w)[6][8], const float* __restrict__ sk,
        float (&ac0)[4], float (&ac1)[4]) {
    (off_one<TH, PP, OOs>(w, sk, ac0, ac1), ...);
}

template<int TH, int PP>
__device__ __forceinline__ void do_plane(const float* __restrict__ wb,
        const float* __restrict__ sk, float (&ac0)[4], float (&ac1)[4]) {
    constexpr int plane = (TH + PP - 1 + OR_) & 7;
    float w[6][8];
    const float* __restrict__ base = wb + plane * PPL_;
    #pragma unroll
    for (int r = 0; r < 6; ++r) {
        *(float4*)&w[r][0] = *(const float4*)&base[r * PW_];
        *(float4*)&w[r][4] = *(const float4*)&base[r * PW_ + 4];
    }
    off_nine<TH, PP>(std::make_integer_sequence<int, 9>{}, w, sk, ac0, ac1);
}

template<int TH>
__device__ __forceinline__ void dil_theta(const float* __restrict__ wb,
        const float* __restrict__ sk, float (&ac0)[4], float (&ac1)[4]) {
    do_plane<TH, 0>(wb, sk, ac0, ac1);
    do_plane<TH, 1>(wb, sk, ac0, ac1);
    do_plane<TH, 2>(wb, sk, ac0, ac1);
}

// One block per (c,theta, 64x32 tile): windows straight from padded global.
__global__ __launch_bounds__(256) void dil_kernel(
        const float* __restrict__ wsA, const float* __restrict__ mp,
        float* __restrict__ out) {
    __shared__ float s_k[27];

    const int z = blockIdx.z;
    const int c  = z >> 3;
    const int th = z & 7;
    const int t = threadIdx.x;

    if (t < 27) {
        const int hti = t / 9 - 1;
        const int hyi = (t / 3) % 3 - 1;
        const int hxi = t % 3 - 1;
        const float hx = (float)hxi, hy = (float)hyi;
        const float hth  = (float)hti * (2.0f * PI_F / OR_);
        const float half = 0.5f * hth;
        float q;
        if (fabsf(half) < 1e-4f) q = 1.0f - half * half * (1.0f / 3.0f);
        else                     q = half / tanf(half);
        const float c1 = q * hx + half * hy;
        const float c2 = -half * hx + q * hy;
        const float c3 = hth;
        const float m0 = mp[c * 3 + 0], m1 = mp[c * 3 + 1], m2 = mp[c * 3 + 2];
        const float d2 = (m0 * c1) * (m0 * c1) + (m1 * c2) * (m1 * c2) + (m2 * c3) * (m2 * c3);
        const float ee = 2.0f * 0.65f / (2.0f * 0.65f - 1.0f);
        const float nu = (2.0f * 0.65f - 1.0f) * powf(2.0f * 0.65f, -ee);
        s_k[t] = nu * powf(d2, 0.5f * ee);
    }
    __syncthreads();

    const int xg = t & 15;                       // 4 px: gx..gx+3
    const int ry = t >> 4;                       // 0..15, 2 rows each
    const int gx = blockIdx.x * 64 + xg * 4;
    const int gy = blockIdx.y * 32 + ry * 2;

    // window base: padded (gy, gx) == image (gy-2, gx-2); 16B aligned
    const float* __restrict__ wb = wsA + c * OR_ * PPL_ + gy * PW_ + gx;

    float ac0[4], ac1[4];
    #pragma unroll
    for (int j = 0; j < 4; ++j) { ac0[j] = -INFINITY; ac1[j] = -INFINITY; }

    switch (th) {
        case 0: dil_theta<0>(wb, s_k, ac0, ac1); break;
        case 1: dil_theta<1>(wb, s_k, ac0, ac1); break;
        case 2: dil_theta<2>(wb, s_k, ac0, ac1); break;
        case 3: dil_theta<3>(wb, s_k, ac0, ac1); break;
        case 4: dil_theta<4>(wb, s_k, ac0, ac1); break;
        case 5: dil_theta<5>(wb, s_k, ac0, ac1); break;
        case 6: dil_theta<6>(wb, s_k, ac0, ac1); break;
        case 7: dil_theta<7>(wb, s_k, ac0, ac1); break;
        default: __builtin_unreachable();
    }

    float* __restrict__ op = out + c * CH_ + th * HW_ + gy * W_ + gx;
    float4 r0, r1;
    r0.x = ac0[0]; r0.y = ac0[1]; r0.z = ac0[2]; r0.w = ac0[3];
    r1.x = ac1[0]; r1.y = ac1[1]; r1.z = ac1[2]; r1.w = ac1[3];
    *(float4*)op = r0;
    *(float4*)(op + W_) = r1;
}

} // anonymous namespace

extern "C" void kernel_launch(void* const* d_in, const int* in_sizes, int n_in,
                              void* d_out, int out_size, void* d_ws, size_t ws_size,
                              hipStream_t stream) {
    const float* u   = (const float*)d_in[0];
    const float* g0  = (const float*)d_in[1];
    const float* mpp = (const float*)d_in[2];
    float* out = (float*)d_out;
    float* wsA = (float*)d_ws;                       // padded conv output, 20.9 MB
    float* wsB = wsA + NPL_ * PPL_;                  // unpadded dil-1 output, 18.9 MB

    dim3 grid(W_ / 64, H_ / 32, C_ * OR_);           // 2304 blocks
    dim3 block(256);

    // iter 1
    conv_kernel<<<grid, block, 0, stream>>>(u,   g0,  wsA);
    dil_kernel <<<grid, block, 0, stream>>>(wsA, mpp, wsB);
    // iter 2
    conv_kernel<<<grid, block, 0, stream>>>(wsB, g0,  wsA);
    dil_kernel <<<grid, block, 0, stream>>>(wsA, mpp, out);
}

// Round 12
// 68.579 us; speedup vs baseline: 1.0720x; 1.0720x over previous
//
#include <hip/hip_runtime.h>
#include <math.h>
#include <utility>
#include <type_traits>

namespace {

constexpr int C_  = 16;
constexpr int OR_ = 8;
constexpr int H_  = 192;
constexpr int W_  = 192;
constexpr int HW_ = H_ * W_;
constexpr int CH_ = OR_ * HW_;
constexpr float PI_F = 3.14159265358979323846f;

// Padded fp16 conv-output workspace: image px (y,x) -> padded (y+2, x+2).
constexpr int PH_  = 196;
constexpr int PW_  = 208;             // row = 416 B (16B multiple)
constexpr int PPL_ = PH_ * PW_;       // 40768 halves per plane
constexpr int NPL_ = C_ * OR_;        // 128 planes
constexpr int PAD_CELLS = 2 * PW_ + 2 * PW_ + H_ * 16;   // 3904 border cells/plane
constexpr int PAD_PER_BLOCK = 109;    // 36 blocks/plane * 109 >= 3904

typedef _Float16 h4 __attribute__((ext_vector_type(4)));

constexpr float SQ2H = 0.70710678118654752440f;
constexpr float CT8[8] = { 1.0f,  SQ2H,  0.0f, -SQ2H, -1.0f, -SQ2H,  0.0f,  SQ2H };
constexpr float ST8[8] = { 0.0f,  SQ2H,  1.0f,  SQ2H,  0.0f, -SQ2H, -1.0f, -SQ2H };

constexpr int cfloor(float v) {
    return (v >= 0.0f) ? (int)v : (((float)(int)v == v) ? (int)v : (int)v - 1);
}

// Zero-padded corner fetch (matches reference _sample's per-corner validity).
template<typename SrcT>
__device__ __forceinline__ float cornerT(const SrcT* __restrict__ p, int iy, int ix) {
    bool valid = ((unsigned)iy < (unsigned)H_) && ((unsigned)ix < (unsigned)W_);
    int yc = min(max(iy, 0), H_ - 1);
    int xc = min(max(ix, 0), W_ - 1);
    float v = (float)p[yc * W_ + xc];
    return valid ? v : 0.0f;
}

// ---------------- convection_m2 (round-9 structure, fp16 padded output) -------
// Also zeroes this block's slice of the pad border (idempotent).
template<typename SrcT>
__global__ __launch_bounds__(256) void conv_kernel(
        const SrcT* __restrict__ u, const float* __restrict__ g0,
        _Float16* __restrict__ wsA) {
    const int t = threadIdx.x;
    const int tx  = t & 63;
    const int ty0 = (t >> 6) * 4;
    const int x   = blockIdx.x * 64 + tx;
    const int y0  = blockIdx.y * 16 + ty0;
    const int z = blockIdx.z;
    const int c  = z >> 3;
    const int th = z & 7;

    // ---- pad-border zeroing (36 blocks/plane x 109 cells) ----
    {
        const int bi = blockIdx.y * 3 + blockIdx.x;          // 0..35
        const int idx = bi * PAD_PER_BLOCK + t;
        if (t < PAD_PER_BLOCK && idx < PAD_CELLS) {
            int i = idx, r, col;
            if (i < 2 * PW_)      { r = i / PW_;            col = i % PW_; }
            else if (i < 4 * PW_) { i -= 2 * PW_; r = 194 + i / PW_; col = i % PW_; }
            else { i -= 4 * PW_; r = 2 + (i >> 4); const int cs = i & 15;
                   col = (cs < 2) ? cs : (192 + cs); }
            wsA[z * PPL_ + r * PW_ + col] = (_Float16)0.0f;
        }
    }

    const float gx0  = g0[c * 3 + 0];
    const float gy0  = g0[c * 3 + 1];
    const float gth0 = g0[c * 3 + 2];

    float sa, ca;
    sincosf((float)th * (2.0f * PI_F / OR_) - gth0, &sa, &ca);
    const float dxs = ca * gx0 - sa * gy0;
    const float dys = sa * gx0 + ca * gy0;

    const float fx = (float)x - dxs;
    const float fy = (float)y0 - dys;
    const float fx0 = floorf(fx), fy0 = floorf(fy);
    const float wx = fx - fx0, wy = fy - fy0;
    const int ix0 = (int)fx0, iy0 = (int)fy0;

    float tc = (float)th - gth0 * (OR_ / (2.0f * PI_F));
    tc = tc - floorf(tc * (1.0f / OR_)) * (float)OR_;
    const float t0f = floorf(tc);
    const float wt = tc - t0f;
    const int t0i = ((int)t0f) & 7;
    const int t1i = (t0i + 1) & 7;

    const SrcT* __restrict__ p0 = u + c * CH_ + t0i * HW_;
    const SrcT* __restrict__ p1 = u + c * CH_ + t1i * HW_;

    float r0, r1, r2, r3;
    if (ix0 >= 0 && ix0 + 1 < W_ && iy0 >= 0 && iy0 + 4 < H_) {
        const int o = iy0 * W_ + ix0;
        float a00 = p0[o],          a01 = p0[o + 1];
        float a10 = p0[o + W_],     a11 = p0[o + W_ + 1];
        float a20 = p0[o + 2 * W_], a21 = p0[o + 2 * W_ + 1];
        float a30 = p0[o + 3 * W_], a31 = p0[o + 3 * W_ + 1];
        float a40 = p0[o + 4 * W_], a41 = p0[o + 4 * W_ + 1];
        float b00 = p1[o],          b01 = p1[o + 1];
        float b10 = p1[o + W_],     b11 = p1[o + W_ + 1];
        float b20 = p1[o + 2 * W_], b21 = p1[o + 2 * W_ + 1];
        float b30 = p1[o + 3 * W_], b31 = p1[o + 3 * W_ + 1];
        float b40 = p1[o + 4 * W_], b41 = p1[o + 4 * W_ + 1];
        float ha0 = a00 + wx * (a01 - a00);
        float ha1 = a10 + wx * (a11 - a10);
        float ha2 = a20 + wx * (a21 - a20);
        float ha3 = a30 + wx * (a31 - a30);
        float ha4 = a40 + wx * (a41 - a40);
        float hb0 = b00 + wx * (b01 - b00);
        float hb1 = b10 + wx * (b11 - b10);
        float hb2 = b20 + wx * (b21 - b20);
        float hb3 = b30 + wx * (b31 - b30);
        float hb4 = b40 + wx * (b41 - b40);
        float va0 = ha0 + wy * (ha1 - ha0);
        float va1 = ha1 + wy * (ha2 - ha1);
        float va2 = ha2 + wy * (ha3 - ha2);
        float va3 = ha3 + wy * (ha4 - ha3);
        float vb0 = hb0 + wy * (hb1 - hb0);
        float vb1 = hb1 + wy * (hb2 - hb1);
        float vb2 = hb2 + wy * (hb3 - hb2);
        float vb3 = hb3 + wy * (hb4 - hb3);
        r0 = va0 + wt * (vb0 - va0);
        r1 = va1 + wt * (vb1 - va1);
        r2 = va2 + wt * (vb2 - va2);
        r3 = va3 + wt * (vb3 - va3);
    } else {
        const float w00 = (1.f - wy) * (1.f - wx);
        const float w01 = (1.f - wy) * wx;
        const float w10 = wy * (1.f - wx);
        const float w11 = wy * wx;
        float rr[4];
        #pragma unroll
        for (int j = 0; j < 4; ++j) {
            const int iy = iy0 + j;
            float v0 = w00 * cornerT(p0, iy, ix0)     + w01 * cornerT(p0, iy, ix0 + 1)
                     + w10 * cornerT(p0, iy + 1, ix0) + w11 * cornerT(p0, iy + 1, ix0 + 1);
            float v1 = w00 * cornerT(p1, iy, ix0)     + w01 * cornerT(p1, iy, ix0 + 1)
                     + w10 * cornerT(p1, iy + 1, ix0) + w11 * cornerT(p1, iy + 1, ix0 + 1);
            rr[j] = v0 + wt * (v1 - v0);
        }
        r0 = rr[0]; r1 = rr[1]; r2 = rr[2]; r3 = rr[3];
    }
    _Float16* __restrict__ op = wsA + z * PPL_ + (y0 + 2) * PW_ + (x + 2);
    op[0]       = (_Float16)r0;
    op[PW_]     = (_Float16)r1;
    op[2 * PW_] = (_Float16)r2;
    op[3 * PW_] = (_Float16)r3;
}

// ---------------- dilation (round-9 structure, fp16 windows) ------------------
template<int TH, int PP, int OO>
__device__ __forceinline__ void off_one(const float (&w)[5][8],
                                        const float* __restrict__ sk, float (&acc)[4]) {
    constexpr int hxi = OO % 3 - 1;
    constexpr int hyi = OO / 3 - 1;
    constexpr float ct = CT8[TH];
    constexpr float st = ST8[TH];
    constexpr float sx = ct * (float)hxi - st * (float)hyi;
    constexpr float sy = st * (float)hxi + ct * (float)hyi;
    constexpr int dx = cfloor(sx);
    constexpr int dy = cfloor(sy);
    constexpr float wx = sx - (float)dx;
    constexpr float wy = sy - (float)dy;
    constexpr int R  = dy + 2;
    constexpr int Cb = dx + 2;

    const float k = sk[PP * 9 + OO];   // wave-uniform LDS broadcast
    #pragma unroll
    for (int j = 0; j < 4; ++j) {
        float v;
        if constexpr (wx == 0.0f && wy == 0.0f) {
            v = w[R][Cb + j];
        } else if constexpr (wy == 0.0f) {
            const float a = w[R][Cb + j];
            v = a + wx * (w[R][Cb + j + 1] - a);
        } else if constexpr (wx == 0.0f) {
            const float a = w[R][Cb + j];
            v = a + wy * (w[R + 1][Cb + j] - a);
        } else {
            const float a0 = w[R][Cb + j];
            const float h0 = a0 + wx * (w[R][Cb + j + 1] - a0);
            const float a1 = w[R + 1][Cb + j];
            const float h1 = a1 + wx * (w[R + 1][Cb + j + 1] - a1);
            v = h0 + wy * (h1 - h0);
        }
        acc[j] = fmaxf(acc[j], v - k);
    }
}

template<int TH, int PP, int... OOs>
__device__ __forceinline__ void off_nine(std::integer_sequence<int, OOs...>,
        const float (&w)[5][8], const float* __restrict__ sk, float (&acc)[4]) {
    (off_one<TH, PP, OOs>(w, sk, acc), ...);
}

// Plane slot PP (hti = PP-1): 10 x 8B fp16 loads -> f32 window.
template<int TH, int PP>
__device__ __forceinline__ void do_plane(const _Float16* __restrict__ winbase,
                                         const float* __restrict__ sk, float (&acc)[4]) {
    constexpr int plane = (TH + PP - 1 + OR_) & 7;
    float w[5][8];
    const _Float16* __restrict__ base = winbase + plane * PPL_;
    #pragma unroll
    for (int r = 0; r < 5; ++r) {
        const h4 lo = *(const h4*)&base[r * PW_];
        const h4 hi = *(const h4*)&base[r * PW_ + 4];
        #pragma unroll
        for (int j = 0; j < 4; ++j) {
            w[r][j]     = (float)lo[j];
            w[r][4 + j] = (float)hi[j];
        }
    }
    off_nine<TH, PP>(std::make_integer_sequence<int, 9>{}, w, sk, acc);
}

template<int TH>
__device__ __forceinline__ void dil_theta(const _Float16* __restrict__ winbase,
        const float* __restrict__ sk, float (&acc)[4]) {
    do_plane<TH, 0>(winbase, sk, acc);
    do_plane<TH, 1>(winbase, sk, acc);
    do_plane<TH, 2>(winbase, sk, acc);
}

// One block per (c,theta): windows straight from padded fp16 global.
template<typename DstT>
__global__ __launch_bounds__(256) void dil_kernel(
        const _Float16* __restrict__ wsA, const float* __restrict__ mp,
        DstT* __restrict__ out) {
    __shared__ float s_k[27];

    const int z = blockIdx.z;
    const int c  = z >> 3;
    const int th = z & 7;
    const int t = threadIdx.x;

    if (t < 27) {
        const int hti = t / 9 - 1;
        const int hyi = (t / 3) % 3 - 1;
        const int hxi = t % 3 - 1;
        const float hx = (float)hxi, hy = (float)hyi;
        const float hth  = (float)hti * (2.0f * PI_F / OR_);
        const float half = 0.5f * hth;
        float q;
        if (fabsf(half) < 1e-4f) q = 1.0f - half * half * (1.0f / 3.0f);
        else                     q = half / tanf(half);
        const float c1 = q * hx + half * hy;
        const float c2 = -half * hx + q * hy;
        const float c3 = hth;
        const float m0 = mp[c * 3 + 0], m1 = mp[c * 3 + 1], m2 = mp[c * 3 + 2];
        const float d2 = (m0 * c1) * (m0 * c1) + (m1 * c2) * (m1 * c2) + (m2 * c3) * (m2 * c3);
        const float ee = 2.0f * 0.65f / (2.0f * 0.65f - 1.0f);
        const float nu = (2.0f * 0.65f - 1.0f) * powf(2.0f * 0.65f, -ee);
        s_k[t] = nu * powf(d2, 0.5f * ee);
    }
    __syncthreads();

    const int xg = t & 15;                       // 4 px: gx..gx+3
    const int y  = t >> 4;                       // row 0..15
    const int gx = blockIdx.x * 64 + xg * 4;
    const int gy = blockIdx.y * 16 + y;

    const _Float16* __restrict__ winbase = wsA + c * OR_ * PPL_ + gy * PW_ + gx;

    float acc[4];
    #pragma unroll
    for (int j = 0; j < 4; ++j) acc[j] = -INFINITY;

    switch (th) {
        case 0: dil_theta<0>(winbase, s_k, acc); break;
        case 1: dil_theta<1>(winbase, s_k, acc); break;
        case 2: dil_theta<2>(winbase, s_k, acc); break;
        case 3: dil_theta<3>(winbase, s_k, acc); break;
        case 4: dil_theta<4>(winbase, s_k, acc); break;
        case 5: dil_theta<5>(winbase, s_k, acc); break;
        case 6: dil_theta<6>(winbase, s_k, acc); break;
        case 7: dil_theta<7>(winbase, s_k, acc); break;
        default: __builtin_unreachable();
    }

    const int o = c * CH_ + th * HW_ + gy * W_ + gx;
    if constexpr (std::is_same_v<DstT, float>) {
        float4 r;
        r.x = acc[0]; r.y = acc[1]; r.z = acc[2]; r.w = acc[3];
        *(float4*)&out[o] = r;
    } else {
        h4 r;
        r[0] = (_Float16)acc[0]; r[1] = (_Float16)acc[1];
        r[2] = (_Float16)acc[2]; r[3] = (_Float16)acc[3];
        *(h4*)&out[o] = r;
    }
}

} // anonymous namespace

extern "C" void kernel_launch(void* const* d_in, const int* in_sizes, int n_in,
                              void* d_out, int out_size, void* d_ws, size_t ws_size,
                              hipStream_t stream) {
    const float* u   = (const float*)d_in[0];
    const float* g0  = (const float*)d_in[1];
    const float* mpp = (const float*)d_in[2];
    float* out = (float*)d_out;
    _Float16* wsA = (_Float16*)d_ws;                 // padded fp16 conv output, 10.4 MB
    _Float16* wsB = wsA + NPL_ * PPL_;               // fp16 dil-1 output, 9.4 MB

    dim3 grid(W_ / 64, H_ / 16, C_ * OR_);           // 4608 blocks
    dim3 block(256);

    // iter 1
    conv_kernel<float>   <<<grid, block, 0, stream>>>(u,   g0,  wsA);
    dil_kernel<_Float16> <<<grid, block, 0, stream>>>(wsA, mpp, wsB);
    // iter 2
    conv_kernel<_Float16><<<grid, block, 0, stream>>>(wsB, g0,  wsA);
    dil_kernel<float>    <<<grid, block, 0, stream>>>(wsA, mpp, out);
}

// Round 13
// 65.779 us; speedup vs baseline: 1.1176x; 1.0426x over previous
//
#include <hip/hip_runtime.h>
#include <math.h>
#include <utility>
#include <type_traits>

namespace {

constexpr int C_  = 16;
constexpr int OR_ = 8;
constexpr int H_  = 192;
constexpr int W_  = 192;
constexpr int HW_ = H_ * W_;
constexpr int CH_ = OR_ * HW_;
constexpr float PI_F = 3.14159265358979323846f;

// Padded fp16 conv-output workspace: image px (y,x) -> padded (y+2, x+2).
constexpr int PH_  = 196;
constexpr int PW_  = 208;             // row = 416 B (16B multiple)
constexpr int PPL_ = PH_ * PW_;       // 40768 halves per plane
constexpr int NPL_ = C_ * OR_;        // 128 planes
constexpr int PAD_CELLS = 2 * PW_ + 2 * PW_ + H_ * 16;   // 3904 border cells/plane
constexpr int PAD_PER_BLOCK = 109;    // 36 blocks/plane * 109 >= 3904

typedef _Float16 h4 __attribute__((ext_vector_type(4)));

constexpr float SQ2H = 0.70710678118654752440f;
constexpr float CT8[8] = { 1.0f,  SQ2H,  0.0f, -SQ2H, -1.0f, -SQ2H,  0.0f,  SQ2H };
constexpr float ST8[8] = { 0.0f,  SQ2H,  1.0f,  SQ2H,  0.0f, -SQ2H, -1.0f, -SQ2H };

constexpr int cfloor(float v) {
    return (v >= 0.0f) ? (int)v : (((float)(int)v == v) ? (int)v : (int)v - 1);
}

// Zero-padded corner fetch (matches reference _sample's per-corner validity).
template<typename SrcT>
__device__ __forceinline__ float cornerT(const SrcT* __restrict__ p, int iy, int ix) {
    bool valid = ((unsigned)iy < (unsigned)H_) && ((unsigned)ix < (unsigned)W_);
    int yc = min(max(iy, 0), H_ - 1);
    int xc = min(max(ix, 0), W_ - 1);
    float v = (float)p[yc * W_ + xc];
    return valid ? v : 0.0f;
}

// ---------------- convection_m2 (round-11 kernel, unchanged) ------------------
template<typename SrcT>
__global__ __launch_bounds__(256) void conv_kernel(
        const SrcT* __restrict__ u, const float* __restrict__ g0,
        _Float16* __restrict__ wsA) {
    const int t = threadIdx.x;
    const int tx  = t & 63;
    const int ty0 = (t >> 6) * 4;
    const int x   = blockIdx.x * 64 + tx;
    const int y0  = blockIdx.y * 16 + ty0;
    const int z = blockIdx.z;
    const int c  = z >> 3;
    const int th = z & 7;

    // ---- pad-border zeroing (36 blocks/plane x 109 cells) ----
    {
        const int bi = blockIdx.y * 3 + blockIdx.x;          // 0..35
        const int idx = bi * PAD_PER_BLOCK + t;
        if (t < PAD_PER_BLOCK && idx < PAD_CELLS) {
            int i = idx, r, col;
            if (i < 2 * PW_)      { r = i / PW_;            col = i % PW_; }
            else if (i < 4 * PW_) { i -= 2 * PW_; r = 194 + i / PW_; col = i % PW_; }
            else { i -= 4 * PW_; r = 2 + (i >> 4); const int cs = i & 15;
                   col = (cs < 2) ? cs : (192 + cs); }
            wsA[z * PPL_ + r * PW_ + col] = (_Float16)0.0f;
        }
    }

    const float gx0  = g0[c * 3 + 0];
    const float gy0  = g0[c * 3 + 1];
    const float gth0 = g0[c * 3 + 2];

    float sa, ca;
    sincosf((float)th * (2.0f * PI_F / OR_) - gth0, &sa, &ca);
    const float dxs = ca * gx0 - sa * gy0;
    const float dys = sa * gx0 + ca * gy0;

    const float fx = (float)x - dxs;
    const float fy = (float)y0 - dys;
    const float fx0 = floorf(fx), fy0 = floorf(fy);
    const float wx = fx - fx0, wy = fy - fy0;
    const int ix0 = (int)fx0, iy0 = (int)fy0;

    float tc = (float)th - gth0 * (OR_ / (2.0f * PI_F));
    tc = tc - floorf(tc * (1.0f / OR_)) * (float)OR_;
    const float t0f = floorf(tc);
    const float wt = tc - t0f;
    const int t0i = ((int)t0f) & 7;
    const int t1i = (t0i + 1) & 7;

    const SrcT* __restrict__ p0 = u + c * CH_ + t0i * HW_;
    const SrcT* __restrict__ p1 = u + c * CH_ + t1i * HW_;

    float r0, r1, r2, r3;
    if (ix0 >= 0 && ix0 + 1 < W_ && iy0 >= 0 && iy0 + 4 < H_) {
        const int o = iy0 * W_ + ix0;
        float a00 = p0[o],          a01 = p0[o + 1];
        float a10 = p0[o + W_],     a11 = p0[o + W_ + 1];
        float a20 = p0[o + 2 * W_], a21 = p0[o + 2 * W_ + 1];
        float a30 = p0[o + 3 * W_], a31 = p0[o + 3 * W_ + 1];
        float a40 = p0[o + 4 * W_], a41 = p0[o + 4 * W_ + 1];
        float b00 = p1[o],          b01 = p1[o + 1];
        float b10 = p1[o + W_],     b11 = p1[o + W_ + 1];
        float b20 = p1[o + 2 * W_], b21 = p1[o + 2 * W_ + 1];
        float b30 = p1[o + 3 * W_], b31 = p1[o + 3 * W_ + 1];
        float b40 = p1[o + 4 * W_], b41 = p1[o + 4 * W_ + 1];
        float ha0 = a00 + wx * (a01 - a00);
        float ha1 = a10 + wx * (a11 - a10);
        float ha2 = a20 + wx * (a21 - a20);
        float ha3 = a30 + wx * (a31 - a30);
        float ha4 = a40 + wx * (a41 - a40);
        float hb0 = b00 + wx * (b01 - b00);
        float hb1 = b10 + wx * (b11 - b10);
        float hb2 = b20 + wx * (b21 - b20);
        float hb3 = b30 + wx * (b31 - b30);
        float hb4 = b40 + wx * (b41 - b40);
        float va0 = ha0 + wy * (ha1 - ha0);
        float va1 = ha1 + wy * (ha2 - ha1);
        float va2 = ha2 + wy * (ha3 - ha2);
        float va3 = ha3 + wy * (ha4 - ha3);
        float vb0 = hb0 + wy * (hb1 - hb0);
        float vb1 = hb1 + wy * (hb2 - hb1);
        float vb2 = hb2 + wy * (hb3 - hb2);
        float vb3 = hb3 + wy * (hb4 - hb3);
        r0 = va0 + wt * (vb0 - va0);
        r1 = va1 + wt * (vb1 - va1);
        r2 = va2 + wt * (vb2 - va2);
        r3 = va3 + wt * (vb3 - va3);
    } else {
        const float w00 = (1.f - wy) * (1.f - wx);
        const float w01 = (1.f - wy) * wx;
        const float w10 = wy * (1.f - wx);
        const float w11 = wy * wx;
        float rr[4];
        #pragma unroll
        for (int j = 0; j < 4; ++j) {
            const int iy = iy0 + j;
            float v0 = w00 * cornerT(p0, iy, ix0)     + w01 * cornerT(p0, iy, ix0 + 1)
                     + w10 * cornerT(p0, iy + 1, ix0) + w11 * cornerT(p0, iy + 1, ix0 + 1);
            float v1 = w00 * cornerT(p1, iy, ix0)     + w01 * cornerT(p1, iy, ix0 + 1)
                     + w10 * cornerT(p1, iy + 1, ix0) + w11 * cornerT(p1, iy + 1, ix0 + 1);
            rr[j] = v0 + wt * (v1 - v0);
        }
        r0 = rr[0]; r1 = rr[1]; r2 = rr[2]; r3 = rr[3];
    }
    _Float16* __restrict__ op = wsA + z * PPL_ + (y0 + 2) * PW_ + (x + 2);
    op[0]       = (_Float16)r0;
    op[PW_]     = (_Float16)r1;
    op[2 * PW_] = (_Float16)r2;
    op[3 * PW_] = (_Float16)r3;
}

// ---------------- dilation: 4x2 px per thread, 6x8 windows (fp16 ws) ----------
template<int TH, int PP, int OO>
__device__ __forceinline__ void off_one(const float (&w)[6][8],
        const float* __restrict__ sk, float (&ac0)[4], float (&ac1)[4]) {
    constexpr int hxi = OO % 3 - 1;
    constexpr int hyi = OO / 3 - 1;
    constexpr float ct = CT8[TH];
    constexpr float st = ST8[TH];
    constexpr float sx = ct * (float)hxi - st * (float)hyi;
    constexpr float sy = st * (float)hxi + ct * (float)hyi;
    constexpr int dx = cfloor(sx);
    constexpr int dy = cfloor(sy);
    constexpr float wx = sx - (float)dx;
    constexpr float wy = sy - (float)dy;
    constexpr int R  = dy + 2;    // 0..3
    constexpr int Cb = dx + 2;    // 0..3

    const float k = sk[PP * 9 + OO];   // wave-uniform LDS broadcast
    #pragma unroll
    for (int j = 0; j < 4; ++j) {
        float v0, v1;
        if constexpr (wx == 0.0f && wy == 0.0f) {
            v0 = w[R][Cb + j];
            v1 = w[R + 1][Cb + j];
        } else if constexpr (wy == 0.0f) {
            const float a = w[R][Cb + j],     a1 = w[R][Cb + j + 1];
            const float b = w[R + 1][Cb + j], b1 = w[R + 1][Cb + j + 1];
            v0 = a + wx * (a1 - a);
            v1 = b + wx * (b1 - b);
        } else if constexpr (wx == 0.0f) {
            const float a  = w[R][Cb + j];
            const float b  = w[R + 1][Cb + j];
            const float cc = w[R + 2][Cb + j];
            v0 = a + wy * (b - a);
            v1 = b + wy * (cc - b);
        } else {
            const float a  = w[R][Cb + j],     a1  = w[R][Cb + j + 1];
            const float b  = w[R + 1][Cb + j], b1  = w[R + 1][Cb + j + 1];
            const float cc = w[R + 2][Cb + j], cc1 = w[R + 2][Cb + j + 1];
            const float h0 = a  + wx * (a1 - a);
            const float h1 = b  + wx * (b1 - b);      // shared by both rows
            const float h2 = cc + wx * (cc1 - cc);
            v0 = h0 + wy * (h1 - h0);
            v1 = h1 + wy * (h2 - h1);
        }
        ac0[j] = fmaxf(ac0[j], v0 - k);
        ac1[j] = fmaxf(ac1[j], v1 - k);
    }
}

template<int TH, int PP, int... OOs>
__device__ __forceinline__ void off_nine(std::integer_sequence<int, OOs...>,
        const float (&w)[6][8], const float* __restrict__ sk,
        float (&ac0)[4], float (&ac1)[4]) {
    (off_one<TH, PP, OOs>(w, sk, ac0, ac1), ...);
}

// Plane slot PP (hti = PP-1): 12 x 8B fp16 loads -> f32 6x8 window.
template<int TH, int PP>
__device__ __forceinline__ void do_plane(const _Float16* __restrict__ wb,
        const float* __restrict__ sk, float (&ac0)[4], float (&ac1)[4]) {
    constexpr int plane = (TH + PP - 1 + OR_) & 7;
    float w[6][8];
    const _Float16* __restrict__ base = wb + plane * PPL_;
    #pragma unroll
    for (int r = 0; r < 6; ++r) {
        const h4 lo = *(const h4*)&base[r * PW_];
        const h4 hi = *(const h4*)&base[r * PW_ + 4];
        #pragma unroll
        for (int j = 0; j < 4; ++j) {
            w[r][j]     = (float)lo[j];
            w[r][4 + j] = (float)hi[j];
        }
    }
    off_nine<TH, PP>(std::make_integer_sequence<int, 9>{}, w, sk, ac0, ac1);
}

template<int TH>
__device__ __forceinline__ void dil_theta(const _Float16* __restrict__ wb,
        const float* __restrict__ sk, float (&ac0)[4], float (&ac1)[4]) {
    do_plane<TH, 0>(wb, sk, ac0, ac1);
    do_plane<TH, 1>(wb, sk, ac0, ac1);
    do_plane<TH, 2>(wb, sk, ac0, ac1);
}

// One block per (c,theta, 64x32 tile): windows straight from padded fp16 ws.
template<typename DstT>
__global__ __launch_bounds__(256) void dil_kernel(
        const _Float16* __restrict__ wsA, const float* __restrict__ mp,
        DstT* __restrict__ out) {
    __shared__ float s_k[27];

    const int z = blockIdx.z;
    const int c  = z >> 3;
    const int th = z & 7;
    const int t = threadIdx.x;

    if (t < 27) {
        const int hti = t / 9 - 1;
        const int hyi = (t / 3) % 3 - 1;
        const int hxi = t % 3 - 1;
        const float hx = (float)hxi, hy = (float)hyi;
        const float hth  = (float)hti * (2.0f * PI_F / OR_);
        const float half = 0.5f * hth;
        float q;
        if (fabsf(half) < 1e-4f) q = 1.0f - half * half * (1.0f / 3.0f);
        else                     q = half / tanf(half);
        const float c1 = q * hx + half * hy;
        const float c2 = -half * hx + q * hy;
        const float c3 = hth;
        const float m0 = mp[c * 3 + 0], m1 = mp[c * 3 + 1], m2 = mp[c * 3 + 2];
        const float d2 = (m0 * c1) * (m0 * c1) + (m1 * c2) * (m1 * c2) + (m2 * c3) * (m2 * c3);
        const float ee = 2.0f * 0.65f / (2.0f * 0.65f - 1.0f);
        const float nu = (2.0f * 0.65f - 1.0f) * powf(2.0f * 0.65f, -ee);
        s_k[t] = nu * powf(d2, 0.5f * ee);
    }
    __syncthreads();

    const int xg = t & 15;                       // 4 px: gx..gx+3
    const int ry = t >> 4;                       // 0..15, 2 rows each
    const int gx = blockIdx.x * 64 + xg * 4;
    const int gy = blockIdx.y * 32 + ry * 2;

    // window base: padded (gy, gx) == image (gy-2, gx-2)
    const _Float16* __restrict__ wb = wsA + c * OR_ * PPL_ + gy * PW_ + gx;

    float ac0[4], ac1[4];
    #pragma unroll
    for (int j = 0; j < 4; ++j) { ac0[j] = -INFINITY; ac1[j] = -INFINITY; }

    switch (th) {
        case 0: dil_theta<0>(wb, s_k, ac0, ac1); break;
        case 1: dil_theta<1>(wb, s_k, ac0, ac1); break;
        case 2: dil_theta<2>(wb, s_k, ac0, ac1); break;
        case 3: dil_theta<3>(wb, s_k, ac0, ac1); break;
        case 4: dil_theta<4>(wb, s_k, ac0, ac1); break;
        case 5: dil_theta<5>(wb, s_k, ac0, ac1); break;
        case 6: dil_theta<6>(wb, s_k, ac0, ac1); break;
        case 7: dil_theta<7>(wb, s_k, ac0, ac1); break;
        default: __builtin_unreachable();
    }

    const int o = c * CH_ + th * HW_ + gy * W_ + gx;
    if constexpr (std::is_same_v<DstT, float>) {
        float4 r0, r1;
        r0.x = ac0[0]; r0.y = ac0[1]; r0.z = ac0[2]; r0.w = ac0[3];
        r1.x = ac1[0]; r1.y = ac1[1]; r1.z = ac1[2]; r1.w = ac1[3];
        *(float4*)&out[o] = r0;
        *(float4*)&out[o + W_] = r1;
    } else {
        h4 r0, r1;
        r0[0] = (_Float16)ac0[0]; r0[1] = (_Float16)ac0[1];
        r0[2] = (_Float16)ac0[2]; r0[3] = (_Float16)ac0[3];
        r1[0] = (_Float16)ac1[0]; r1[1] = (_Float16)ac1[1];
        r1[2] = (_Float16)ac1[2]; r1[3] = (_Float16)ac1[3];
        *(h4*)&out[o] = r0;
        *(h4*)&out[o + W_] = r1;
    }
}

} // anonymous namespace

extern "C" void kernel_launch(void* const* d_in, const int* in_sizes, int n_in,
                              void* d_out, int out_size, void* d_ws, size_t ws_size,
                              hipStream_t stream) {
    const float* u   = (const float*)d_in[0];
    const float* g0  = (const float*)d_in[1];
    const float* mpp = (const float*)d_in[2];
    float* out = (float*)d_out;
    _Float16* wsA = (_Float16*)d_ws;                 // padded fp16 conv output, 10.4 MB
    _Float16* wsB = wsA + NPL_ * PPL_;               // fp16 dil-1 output, 9.4 MB

    dim3 cgrid(W_ / 64, H_ / 16, C_ * OR_);          // conv: 4608 blocks
    dim3 dgrid(W_ / 64, H_ / 32, C_ * OR_);          // dil:  2304 blocks
    dim3 block(256);

    // iter 1
    conv_kernel<float>   <<<cgrid, block, 0, stream>>>(u,   g0,  wsA);
    dil_kernel<_Float16> <<<dgrid, block, 0, stream>>>(wsA, mpp, wsB);
    // iter 2
    conv_kernel<_Float16><<<cgrid, block, 0, stream>>>(wsB, g0,  wsA);
    dil_kernel<float>    <<<dgrid, block, 0, stream>>>(wsA, mpp, out);
}